// Round 8
// baseline (79.992 us; speedup 1.0000x reference)
//
#include <hip/hip_runtime.h>
#include <hip/hip_fp8.h>
#include <stdint.h>

#define N_CLS 8192
#define FEAT  512                           // elements; fp8 -> 512 B per row
#define BATCH 1024
#define NTI   32                            // 256-row tiles
#define NTJ   64                            // 128-col tiles
#define NBLK  1056                          // #{(i,j): j in [2i, 64)}
#define NSLOT 16                            // FEAT/32
#define SLOTB 12288                         // bytes/slot: A 256*32 + B 128*32

typedef __attribute__((ext_vector_type(4))) float f32x4;

__device__ inline unsigned char f2fp8(float x) {
    __hip_fp8_e4m3 q(x);                    // OCP e4m3 (gfx950), HW convert
    return q.__x;
}

// ---------------- Kernel 1: sequential EMA per label -> fp8 protos ---------
__global__ __launch_bounds__(256) void ema_kernel(
    const float* __restrict__ features, const int* __restrict__ labels,
    const float* __restrict__ protos,
    unsigned char* __restrict__ Phi8, float* __restrict__ rowsum) {
    const int row  = blockIdx.x * 4 + (threadIdx.x >> 6);
    const int lane = threadIdx.x & 63;
    if (lane == 0) rowsum[row] = 0.f;

    float p[8];
    #pragma unroll
    for (int j = 0; j < 8; ++j) p[j] = protos[(size_t)row * FEAT + j * 64 + lane];

    for (int c = 0; c < BATCH / 64; ++c) {
        int lab = labels[c * 64 + lane];
        unsigned long long m = __ballot(lab == row);
        while (m) {
            int b = __builtin_ctzll(m);     // earliest remaining sample
            m &= m - 1;
            int s = c * 64 + b;
            float ss = 0.f;
            #pragma unroll
            for (int j = 0; j < 8; ++j) {
                float f = features[(size_t)s * FEAT + j * 64 + lane];
                p[j] = p[j] * 0.95f + f * 0.05f;
                ss += p[j] * p[j];
            }
            #pragma unroll
            for (int off = 32; off; off >>= 1) ss += __shfl_xor(ss, off);
            float inv = 1.0f / fmaxf(sqrtf(ss), 1e-12f);
            #pragma unroll
            for (int j = 0; j < 8; ++j) p[j] *= inv;
        }
    }
    #pragma unroll
    for (int j = 0; j < 8; ++j)
        Phi8[(size_t)row * FEAT + j * 64 + lane] = f2fp8(p[j]);
}

// ---------------- Kernel 2: 256x128 rect Gram tiles, fp8, ring-3 -----------
// R7 schedule (ring of 3 K-32 slots, counted vmcnt, 1 barrier/slot, setprio)
// with fp8 operands: LDS bytes and staging halved; MFMA count unchanged.
// K-map per lane is linear (store-side 16B-seg XOR cancelled by read-side),
// identical for A and B -> Gram correct for any true HW k-order.
__global__ __launch_bounds__(512, 4) void gemm_disp_kernel(
    const unsigned char* __restrict__ Phi8, float* __restrict__ rowsum) {
    __shared__ __align__(16) char smem[3 * SLOTB];   // 36 KiB

    // XCD-aware swizzle (1056 = 8*132)
    int bid = blockIdx.x;
    int u = (bid & 7) * (NBLK / 8) + (bid >> 3);
    int i = 0;
    while (u >= NTJ - 2 * i) { u -= NTJ - 2 * i; ++i; }
    const int j = 2 * i + u;                // j >= 2i
    const bool diagovl = ((j >> 1) == i);   // col-range overlaps row-range

    const int w    = threadIdx.x >> 6;      // wave 0..7
    const int lane = threadIdx.x & 63;
    const int wr = w >> 1, wc = w & 1;      // 4x2 waves, 64x64 each
    const int h = lane >> 4;                // k-group 0..3 (8 fp8 each)
    const int r = lane & 15;                // fragment row/col
    // read byte-offset within a 32-B row: 16B-seg (h>>1)^(r&1), half (h&1)
    const int rseg = ((h >> 1) ^ (r & 1)) * 16 + (h & 1) * 8;

    const int Ibase = i * 256, Jbase = j * 128;

    f32x4 acc[4][4];
    #pragma unroll
    for (int m = 0; m < 4; ++m)
        #pragma unroll
        for (int n = 0; n < 4; ++n) acc[m][n] = (f32x4){0.f, 0.f, 0.f, 0.f};

    // staging: A 8 KB = 8 waves x 1 load (rows w*32..w*32+31); B 4 KB =
    // waves 4..7 x 1 load. Lane covers row base+(lane>>1), 16B-seg lane&1;
    // global seg pre-swizzled by row parity (store-XOR == read-XOR).
    const int sg = (lane & 1) ^ ((lane >> 1) & 1);
    const unsigned char* gA =
        Phi8 + (size_t)(Ibase + w * 32 + (lane >> 1)) * FEAT + sg * 16;
    const unsigned char* gB =
        Phi8 + (size_t)(Jbase + (w & 3) * 32 + (lane >> 1)) * FEAT + sg * 16;

#define STAGE(s)                                                              \
    {                                                                         \
        char* la = smem + ((s) % 3) * SLOTB + w * 1024;                       \
        __builtin_amdgcn_global_load_lds(                                     \
            (const __attribute__((address_space(1))) void*)(gA + (s) * 32),   \
            (__attribute__((address_space(3))) void*)la, 16, 0, 0);           \
        if (w >= 4) {                                                         \
            char* lb = smem + ((s) % 3) * SLOTB + 8192 + (w & 3) * 1024;      \
            __builtin_amdgcn_global_load_lds(                                 \
                (const __attribute__((address_space(1))) void*)(gB + (s) * 32),\
                (__attribute__((address_space(3))) void*)lb, 16, 0, 0);       \
        }                                                                     \
    }

#define SLOT(s, TAIL)                                                         \
    {                                                                         \
        const char* As = smem + ((s) % 3) * SLOTB;                            \
        const char* Bs = As + 8192;                                           \
        long a0, a1, a2, a3, b0, b1, b2, b3;                                  \
        b0 = *(const long*)(Bs + (wc * 64 +  0 + r) * 32 + rseg);             \
        b1 = *(const long*)(Bs + (wc * 64 + 16 + r) * 32 + rseg);             \
        b2 = *(const long*)(Bs + (wc * 64 + 32 + r) * 32 + rseg);             \
        b3 = *(const long*)(Bs + (wc * 64 + 48 + r) * 32 + rseg);             \
        a0 = *(const long*)(As + (wr * 64 +  0 + r) * 32 + rseg);             \
        a1 = *(const long*)(As + (wr * 64 + 16 + r) * 32 + rseg);             \
        a2 = *(const long*)(As + (wr * 64 + 32 + r) * 32 + rseg);             \
        a3 = *(const long*)(As + (wr * 64 + 48 + r) * 32 + rseg);             \
        __builtin_amdgcn_s_setprio(1);                                        \
        acc[0][0] = __builtin_amdgcn_mfma_f32_16x16x32_fp8_fp8(a0, b0, acc[0][0], 0, 0, 0); \
        acc[1][0] = __builtin_amdgcn_mfma_f32_16x16x32_fp8_fp8(a1, b0, acc[1][0], 0, 0, 0); \
        acc[2][0] = __builtin_amdgcn_mfma_f32_16x16x32_fp8_fp8(a2, b0, acc[2][0], 0, 0, 0); \
        acc[3][0] = __builtin_amdgcn_mfma_f32_16x16x32_fp8_fp8(a3, b0, acc[3][0], 0, 0, 0); \
        acc[0][1] = __builtin_amdgcn_mfma_f32_16x16x32_fp8_fp8(a0, b1, acc[0][1], 0, 0, 0); \
        acc[1][1] = __builtin_amdgcn_mfma_f32_16x16x32_fp8_fp8(a1, b1, acc[1][1], 0, 0, 0); \
        acc[2][1] = __builtin_amdgcn_mfma_f32_16x16x32_fp8_fp8(a2, b1, acc[2][1], 0, 0, 0); \
        acc[3][1] = __builtin_amdgcn_mfma_f32_16x16x32_fp8_fp8(a3, b1, acc[3][1], 0, 0, 0); \
        acc[0][2] = __builtin_amdgcn_mfma_f32_16x16x32_fp8_fp8(a0, b2, acc[0][2], 0, 0, 0); \
        acc[1][2] = __builtin_amdgcn_mfma_f32_16x16x32_fp8_fp8(a1, b2, acc[1][2], 0, 0, 0); \
        acc[2][2] = __builtin_amdgcn_mfma_f32_16x16x32_fp8_fp8(a2, b2, acc[2][2], 0, 0, 0); \
        acc[3][2] = __builtin_amdgcn_mfma_f32_16x16x32_fp8_fp8(a3, b2, acc[3][2], 0, 0, 0); \
        acc[0][3] = __builtin_amdgcn_mfma_f32_16x16x32_fp8_fp8(a0, b3, acc[0][3], 0, 0, 0); \
        acc[1][3] = __builtin_amdgcn_mfma_f32_16x16x32_fp8_fp8(a1, b3, acc[1][3], 0, 0, 0); \
        acc[2][3] = __builtin_amdgcn_mfma_f32_16x16x32_fp8_fp8(a2, b3, acc[2][3], 0, 0, 0); \
        acc[3][3] = __builtin_amdgcn_mfma_f32_16x16x32_fp8_fp8(a3, b3, acc[3][3], 0, 0, 0); \
        __builtin_amdgcn_s_setprio(0);                                        \
        TAIL                                                                  \
    }

#define WAITC                                                                 \
    if (w < 4) asm volatile("s_waitcnt vmcnt(1)" ::: "memory");               \
    else       asm volatile("s_waitcnt vmcnt(2)" ::: "memory");

#define TAIL_MID(s)                                                           \
    STAGE((s) + 2)                                                            \
    WAITC                                                                     \
    __builtin_amdgcn_s_barrier();
#define TAIL_14                                                               \
    asm volatile("s_waitcnt vmcnt(0)" ::: "memory");                          \
    __builtin_amdgcn_s_barrier();
#define TAIL_15

    // prologue: stage slots 0,1; wait slot 0 landed (slot 1 stays in flight)
    STAGE(0) STAGE(1)
    WAITC
    __builtin_amdgcn_s_barrier();

    SLOT(0,  TAIL_MID(0))  SLOT(1,  TAIL_MID(1))  SLOT(2,  TAIL_MID(2))
    SLOT(3,  TAIL_MID(3))  SLOT(4,  TAIL_MID(4))  SLOT(5,  TAIL_MID(5))
    SLOT(6,  TAIL_MID(6))  SLOT(7,  TAIL_MID(7))  SLOT(8,  TAIL_MID(8))
    SLOT(9,  TAIL_MID(9))  SLOT(10, TAIL_MID(10)) SLOT(11, TAIL_MID(11))
    SLOT(12, TAIL_MID(12)) SLOT(13, TAIL_MID(13))
    SLOT(14, TAIL_14)
    SLOT(15, TAIL_15)

    // epilogue: e = exp(10*S); zero exact diagonal on overlap blocks
    // D layout: row = 4*h + q, col = r (HW-verified)
    #pragma unroll
    for (int m = 0; m < 4; ++m)
        #pragma unroll
        for (int n = 0; n < 4; ++n)
            #pragma unroll
            for (int q = 0; q < 4; ++q) {
                float v = __expf(acc[m][n][q] * 10.0f);
                if (diagovl &&
                    (Ibase + wr * 64 + m * 16 + h * 4 + q) ==
                    (Jbase + wc * 64 + n * 16 + r))
                    v = 0.f;
                acc[m][n][q] = v;
            }

    // row credit (always): rowsum[Ibase + wr*64 + m*16 + 4h+q]
    #pragma unroll
    for (int m = 0; m < 4; ++m) {
        float rs[4];
        #pragma unroll
        for (int q = 0; q < 4; ++q)
            rs[q] = acc[m][0][q] + acc[m][1][q] + acc[m][2][q] + acc[m][3][q];
        #pragma unroll
        for (int q = 0; q < 4; ++q)
            #pragma unroll
            for (int off = 1; off < 16; off <<= 1) rs[q] += __shfl_xor(rs[q], off);
        if (r == 0) {
            #pragma unroll
            for (int q = 0; q < 4; ++q)
                atomicAdd(&rowsum[Ibase + wr * 64 + m * 16 + h * 4 + q], rs[q]);
        }
    }

    // col credit (only when mirror entry is NOT computed elsewhere): j >= 2i+2
    if (!diagovl) {
        #pragma unroll
        for (int n = 0; n < 4; ++n) {
            float cs = 0.f;
            #pragma unroll
            for (int m = 0; m < 4; ++m)
                #pragma unroll
                for (int q = 0; q < 4; ++q) cs += acc[m][n][q];
            cs += __shfl_xor(cs, 16);
            cs += __shfl_xor(cs, 32);
            if (lane < 16)
                atomicAdd(&rowsum[Jbase + wc * 64 + n * 16 + r], cs);
        }
    }
}

// ---------------- Kernel 3: loss = mean(log(rowsum / (n-1))) ---------------
__global__ __launch_bounds__(512) void loss_kernel(
    const float* __restrict__ rowsum, float* __restrict__ out) {
    __shared__ float red[8];
    float s = 0.f;
    for (int i = threadIdx.x; i < N_CLS; i += 512)
        s += logf(rowsum[i] * (1.0f / (float)(N_CLS - 1)));
    #pragma unroll
    for (int off = 32; off; off >>= 1) s += __shfl_xor(s, off);
    if ((threadIdx.x & 63) == 0) red[threadIdx.x >> 6] = s;
    __syncthreads();
    if (threadIdx.x == 0) {
        float tot = 0.f;
        #pragma unroll
        for (int i = 0; i < 8; ++i) tot += red[i];
        out[0] = tot * (1.0f / (float)N_CLS);
    }
}

extern "C" void kernel_launch(void* const* d_in, const int* in_sizes, int n_in,
                              void* d_out, int out_size, void* d_ws, size_t ws_size,
                              hipStream_t stream) {
    (void)in_sizes; (void)n_in; (void)out_size; (void)ws_size;
    const float* features = (const float*)d_in[0];
    const int*   labels   = (const int*)d_in[1];
    const float* protos   = (const float*)d_in[2];
    float* out = (float*)d_out;

    unsigned char* Phi8 = (unsigned char*)d_ws;                     // 4 MiB
    float* rowsum = (float*)(Phi8 + (size_t)N_CLS * FEAT);          // 32 KiB

    ema_kernel<<<N_CLS / 4, 256, 0, stream>>>(features, labels, protos, Phi8, rowsum);
    gemm_disp_kernel<<<NBLK, 512, 0, stream>>>(Phi8, rowsum);
    loss_kernel<<<1, 512, 0, stream>>>(rowsum, out);
}

// Round 9
// 69.422 us; speedup vs baseline: 1.1523x; 1.1523x over previous
//
#include <hip/hip_runtime.h>
#include <hip/hip_fp8.h>
#include <stdint.h>

#define N_CLS 8192
#define FEAT  512                           // elements; fp8 -> 512 B per row
#define BATCH 1024
#define NTI   32                            // 256-row tiles
#define NTJ   64                            // 128-col tiles
#define NBLK  1056                          // #{(i,j): j in [2i, 64)}
#define NSLOT 16                            // FEAT/32
#define SLOTB 12288                         // bytes/slot: A 256*32 + B 128*32

typedef __attribute__((ext_vector_type(4))) float f32x4;

__device__ inline unsigned char f2fp8(float x) {
    __hip_fp8_e4m3 q(x);                    // OCP e4m3 (gfx950), HW convert
    return q.__x;
}

// ---------------- Kernel 1: sequential EMA per label -> fp8 protos ---------
__global__ __launch_bounds__(256) void ema_kernel(
    const float* __restrict__ features, const int* __restrict__ labels,
    const float* __restrict__ protos,
    unsigned char* __restrict__ Phi8, float* __restrict__ rowsum) {
    const int row  = blockIdx.x * 4 + (threadIdx.x >> 6);
    const int lane = threadIdx.x & 63;
    if (lane == 0) rowsum[row] = 0.f;

    float p[8];
    #pragma unroll
    for (int j = 0; j < 8; ++j) p[j] = protos[(size_t)row * FEAT + j * 64 + lane];

    for (int c = 0; c < BATCH / 64; ++c) {
        int lab = labels[c * 64 + lane];
        unsigned long long m = __ballot(lab == row);
        while (m) {
            int b = __builtin_ctzll(m);     // earliest remaining sample
            m &= m - 1;
            int s = c * 64 + b;
            float ss = 0.f;
            #pragma unroll
            for (int j = 0; j < 8; ++j) {
                float f = features[(size_t)s * FEAT + j * 64 + lane];
                p[j] = p[j] * 0.95f + f * 0.05f;
                ss += p[j] * p[j];
            }
            #pragma unroll
            for (int off = 32; off; off >>= 1) ss += __shfl_xor(ss, off);
            float inv = 1.0f / fmaxf(sqrtf(ss), 1e-12f);
            #pragma unroll
            for (int j = 0; j < 8; ++j) p[j] *= inv;
        }
    }
    #pragma unroll
    for (int j = 0; j < 8; ++j)
        Phi8[(size_t)row * FEAT + j * 64 + lane] = f2fp8(p[j]);
}

// ---------------- Kernel 2: 256x128 rect Gram tiles, fp8, ring-3 -----------
// R7 schedule (ring of 3 K-32 slots, counted vmcnt, 1 barrier/slot, setprio)
// with fp8 operands. Swizzle (fixed R9): 16B-block XOR with (row>>2)&1 --
// bank = (r&3)*8 + ((h>>1)^((r>>2)&1))*4 + (h&1)*2: exactly 4 touches/bank
// full-wave, 2/bank half-wave = b64 minimum -> conflict-free. Read-side XOR
// cancels store-side (fragment row bases are multiples of 16) -> linear k.
__global__ __launch_bounds__(512, 4) void gemm_disp_kernel(
    const unsigned char* __restrict__ Phi8, float* __restrict__ rowsum) {
    __shared__ __align__(16) char smem[3 * SLOTB];   // 36 KiB

    // XCD-aware swizzle (1056 = 8*132)
    int bid = blockIdx.x;
    int u = (bid & 7) * (NBLK / 8) + (bid >> 3);
    int i = 0;
    while (u >= NTJ - 2 * i) { u -= NTJ - 2 * i; ++i; }
    const int j = 2 * i + u;                // j >= 2i
    const bool diagovl = ((j >> 1) == i);   // col-range overlaps row-range

    const int w    = threadIdx.x >> 6;      // wave 0..7
    const int lane = threadIdx.x & 63;
    const int wr = w >> 1, wc = w & 1;      // 4x2 waves, 64x64 each
    const int h = lane >> 4;                // k-group 0..3 (8 fp8 each)
    const int r = lane & 15;                // fragment row/col
    // read byte-offset within a 32-B row (conflict-free, see header comment)
    const int rseg = ((h >> 1) ^ ((r >> 2) & 1)) * 16 + (h & 1) * 8;

    const int Ibase = i * 256, Jbase = j * 128;

    f32x4 acc[4][4];
    #pragma unroll
    for (int m = 0; m < 4; ++m)
        #pragma unroll
        for (int n = 0; n < 4; ++n) acc[m][n] = (f32x4){0.f, 0.f, 0.f, 0.f};

    // staging: A 8 KB = 8 waves x 1 load (rows w*32..w*32+31); B 4 KB =
    // waves 4..7 x 1 load. Lane covers row base+(lane>>1), 16B-block lane&1;
    // source block pre-swizzled by (row>>2)&1 = (lane>>3)&1.
    const int sg = (lane & 1) ^ ((lane >> 3) & 1);
    const unsigned char* gA =
        Phi8 + (size_t)(Ibase + w * 32 + (lane >> 1)) * FEAT + sg * 16;
    const unsigned char* gB =
        Phi8 + (size_t)(Jbase + (w & 3) * 32 + (lane >> 1)) * FEAT + sg * 16;

#define STAGE(s)                                                              \
    {                                                                         \
        char* la = smem + ((s) % 3) * SLOTB + w * 1024;                       \
        __builtin_amdgcn_global_load_lds(                                     \
            (const __attribute__((address_space(1))) void*)(gA + (s) * 32),   \
            (__attribute__((address_space(3))) void*)la, 16, 0, 0);           \
        if (w >= 4) {                                                         \
            char* lb = smem + ((s) % 3) * SLOTB + 8192 + (w & 3) * 1024;      \
            __builtin_amdgcn_global_load_lds(                                 \
                (const __attribute__((address_space(1))) void*)(gB + (s) * 32),\
                (__attribute__((address_space(3))) void*)lb, 16, 0, 0);       \
        }                                                                     \
    }

#define SLOT(s, TAIL)                                                         \
    {                                                                         \
        const char* As = smem + ((s) % 3) * SLOTB;                            \
        const char* Bs = As + 8192;                                           \
        long a0, a1, a2, a3, b0, b1, b2, b3;                                  \
        b0 = *(const long*)(Bs + (wc * 64 +  0 + r) * 32 + rseg);             \
        b1 = *(const long*)(Bs + (wc * 64 + 16 + r) * 32 + rseg);             \
        b2 = *(const long*)(Bs + (wc * 64 + 32 + r) * 32 + rseg);             \
        b3 = *(const long*)(Bs + (wc * 64 + 48 + r) * 32 + rseg);             \
        a0 = *(const long*)(As + (wr * 64 +  0 + r) * 32 + rseg);             \
        a1 = *(const long*)(As + (wr * 64 + 16 + r) * 32 + rseg);             \
        a2 = *(const long*)(As + (wr * 64 + 32 + r) * 32 + rseg);             \
        a3 = *(const long*)(As + (wr * 64 + 48 + r) * 32 + rseg);             \
        __builtin_amdgcn_s_setprio(1);                                        \
        acc[0][0] = __builtin_amdgcn_mfma_f32_16x16x32_fp8_fp8(a0, b0, acc[0][0], 0, 0, 0); \
        acc[1][0] = __builtin_amdgcn_mfma_f32_16x16x32_fp8_fp8(a1, b0, acc[1][0], 0, 0, 0); \
        acc[2][0] = __builtin_amdgcn_mfma_f32_16x16x32_fp8_fp8(a2, b0, acc[2][0], 0, 0, 0); \
        acc[3][0] = __builtin_amdgcn_mfma_f32_16x16x32_fp8_fp8(a3, b0, acc[3][0], 0, 0, 0); \
        acc[0][1] = __builtin_amdgcn_mfma_f32_16x16x32_fp8_fp8(a0, b1, acc[0][1], 0, 0, 0); \
        acc[1][1] = __builtin_amdgcn_mfma_f32_16x16x32_fp8_fp8(a1, b1, acc[1][1], 0, 0, 0); \
        acc[2][1] = __builtin_amdgcn_mfma_f32_16x16x32_fp8_fp8(a2, b1, acc[2][1], 0, 0, 0); \
        acc[3][1] = __builtin_amdgcn_mfma_f32_16x16x32_fp8_fp8(a3, b1, acc[3][1], 0, 0, 0); \
        acc[0][2] = __builtin_amdgcn_mfma_f32_16x16x32_fp8_fp8(a0, b2, acc[0][2], 0, 0, 0); \
        acc[1][2] = __builtin_amdgcn_mfma_f32_16x16x32_fp8_fp8(a1, b2, acc[1][2], 0, 0, 0); \
        acc[2][2] = __builtin_amdgcn_mfma_f32_16x16x32_fp8_fp8(a2, b2, acc[2][2], 0, 0, 0); \
        acc[3][2] = __builtin_amdgcn_mfma_f32_16x16x32_fp8_fp8(a3, b2, acc[3][2], 0, 0, 0); \
        acc[0][3] = __builtin_amdgcn_mfma_f32_16x16x32_fp8_fp8(a0, b3, acc[0][3], 0, 0, 0); \
        acc[1][3] = __builtin_amdgcn_mfma_f32_16x16x32_fp8_fp8(a1, b3, acc[1][3], 0, 0, 0); \
        acc[2][3] = __builtin_amdgcn_mfma_f32_16x16x32_fp8_fp8(a2, b3, acc[2][3], 0, 0, 0); \
        acc[3][3] = __builtin_amdgcn_mfma_f32_16x16x32_fp8_fp8(a3, b3, acc[3][3], 0, 0, 0); \
        __builtin_amdgcn_s_setprio(0);                                        \
        TAIL                                                                  \
    }

#define WAITC                                                                 \
    if (w < 4) asm volatile("s_waitcnt vmcnt(1)" ::: "memory");               \
    else       asm volatile("s_waitcnt vmcnt(2)" ::: "memory");

#define TAIL_MID(s)                                                           \
    STAGE((s) + 2)                                                            \
    WAITC                                                                     \
    __builtin_amdgcn_s_barrier();
#define TAIL_14                                                               \
    asm volatile("s_waitcnt vmcnt(0)" ::: "memory");                          \
    __builtin_amdgcn_s_barrier();
#define TAIL_15

    // prologue: stage slots 0,1; wait slot 0 landed (slot 1 stays in flight)
    STAGE(0) STAGE(1)
    WAITC
    __builtin_amdgcn_s_barrier();

    SLOT(0,  TAIL_MID(0))  SLOT(1,  TAIL_MID(1))  SLOT(2,  TAIL_MID(2))
    SLOT(3,  TAIL_MID(3))  SLOT(4,  TAIL_MID(4))  SLOT(5,  TAIL_MID(5))
    SLOT(6,  TAIL_MID(6))  SLOT(7,  TAIL_MID(7))  SLOT(8,  TAIL_MID(8))
    SLOT(9,  TAIL_MID(9))  SLOT(10, TAIL_MID(10)) SLOT(11, TAIL_MID(11))
    SLOT(12, TAIL_MID(12)) SLOT(13, TAIL_MID(13))
    SLOT(14, TAIL_14)
    SLOT(15, TAIL_15)

    // epilogue: e = exp(10*S); zero exact diagonal on overlap blocks
    // D layout: row = 4*h + q, col = r (HW-verified)
    #pragma unroll
    for (int m = 0; m < 4; ++m)
        #pragma unroll
        for (int n = 0; n < 4; ++n)
            #pragma unroll
            for (int q = 0; q < 4; ++q) {
                float v = __expf(acc[m][n][q] * 10.0f);
                if (diagovl &&
                    (Ibase + wr * 64 + m * 16 + h * 4 + q) ==
                    (Jbase + wc * 64 + n * 16 + r))
                    v = 0.f;
                acc[m][n][q] = v;
            }

    // row credit (always): rowsum[Ibase + wr*64 + m*16 + 4h+q]
    #pragma unroll
    for (int m = 0; m < 4; ++m) {
        float rs[4];
        #pragma unroll
        for (int q = 0; q < 4; ++q)
            rs[q] = acc[m][0][q] + acc[m][1][q] + acc[m][2][q] + acc[m][3][q];
        #pragma unroll
        for (int q = 0; q < 4; ++q)
            #pragma unroll
            for (int off = 1; off < 16; off <<= 1) rs[q] += __shfl_xor(rs[q], off);
        if (r == 0) {
            #pragma unroll
            for (int q = 0; q < 4; ++q)
                atomicAdd(&rowsum[Ibase + wr * 64 + m * 16 + h * 4 + q], rs[q]);
        }
    }

    // col credit (only when mirror entry is NOT computed elsewhere): j >= 2i+2
    if (!diagovl) {
        #pragma unroll
        for (int n = 0; n < 4; ++n) {
            float cs = 0.f;
            #pragma unroll
            for (int m = 0; m < 4; ++m)
                #pragma unroll
                for (int q = 0; q < 4; ++q) cs += acc[m][n][q];
            cs += __shfl_xor(cs, 16);
            cs += __shfl_xor(cs, 32);
            if (lane < 16)
                atomicAdd(&rowsum[Jbase + wc * 64 + n * 16 + r], cs);
        }
    }
}

// ---------------- Kernel 3: loss = mean(log(rowsum / (n-1))) ---------------
__global__ __launch_bounds__(512) void loss_kernel(
    const float* __restrict__ rowsum, float* __restrict__ out) {
    __shared__ float red[8];
    float s = 0.f;
    for (int i = threadIdx.x; i < N_CLS; i += 512)
        s += logf(rowsum[i] * (1.0f / (float)(N_CLS - 1)));
    #pragma unroll
    for (int off = 32; off; off >>= 1) s += __shfl_xor(s, off);
    if ((threadIdx.x & 63) == 0) red[threadIdx.x >> 6] = s;
    __syncthreads();
    if (threadIdx.x == 0) {
        float tot = 0.f;
        #pragma unroll
        for (int i = 0; i < 8; ++i) tot += red[i];
        out[0] = tot * (1.0f / (float)N_CLS);
    }
}

extern "C" void kernel_launch(void* const* d_in, const int* in_sizes, int n_in,
                              void* d_out, int out_size, void* d_ws, size_t ws_size,
                              hipStream_t stream) {
    (void)in_sizes; (void)n_in; (void)out_size; (void)ws_size;
    const float* features = (const float*)d_in[0];
    const int*   labels   = (const int*)d_in[1];
    const float* protos   = (const float*)d_in[2];
    float* out = (float*)d_out;

    unsigned char* Phi8 = (unsigned char*)d_ws;                     // 4 MiB
    float* rowsum = (float*)(Phi8 + (size_t)N_CLS * FEAT);          // 32 KiB

    ema_kernel<<<N_CLS / 4, 256, 0, stream>>>(features, labels, protos, Phi8, rowsum);
    gemm_disp_kernel<<<NBLK, 512, 0, stream>>>(Phi8, rowsum);
    loss_kernel<<<1, 512, 0, stream>>>(rowsum, out);
}

// Round 10
// 58.826 us; speedup vs baseline: 1.3598x; 1.1801x over previous
//
#include <hip/hip_runtime.h>
#include <hip/hip_fp8.h>
#include <stdint.h>

#define N_CLS 8192
#define FEAT  512                           // elements; fp8 -> 512 B per row
#define BATCH 1024
#define NTI   32                            // 256-row tiles
#define NTJ   64                            // 128-col tiles
#define NBLK  1056                          // #{(i,j): j in [2i, 64)}
#define NSLOT 8                             // FEAT/64 (K=64 per slot)
#define SLOTB 24576                         // bytes/slot: A 256*64 + B 128*64

typedef __attribute__((ext_vector_type(4))) float f32x4;
typedef __attribute__((ext_vector_type(2))) long longx2;

__device__ inline unsigned char f2fp8(float x) {
    __hip_fp8_e4m3 q(x);                    // OCP e4m3 (gfx950), HW convert
    return q.__x;
}

// ---------------- Kernel 1: sequential EMA per label -> fp8 protos ---------
__global__ __launch_bounds__(256) void ema_kernel(
    const float* __restrict__ features, const int* __restrict__ labels,
    const float* __restrict__ protos,
    unsigned char* __restrict__ Phi8, float* __restrict__ rowsum) {
    const int row  = blockIdx.x * 4 + (threadIdx.x >> 6);
    const int lane = threadIdx.x & 63;
    if (lane == 0) rowsum[row] = 0.f;

    float p[8];
    #pragma unroll
    for (int j = 0; j < 8; ++j) p[j] = protos[(size_t)row * FEAT + j * 64 + lane];

    for (int c = 0; c < BATCH / 64; ++c) {
        int lab = labels[c * 64 + lane];
        unsigned long long m = __ballot(lab == row);
        while (m) {
            int b = __builtin_ctzll(m);     // earliest remaining sample
            m &= m - 1;
            int s = c * 64 + b;
            float ss = 0.f;
            #pragma unroll
            for (int j = 0; j < 8; ++j) {
                float f = features[(size_t)s * FEAT + j * 64 + lane];
                p[j] = p[j] * 0.95f + f * 0.05f;
                ss += p[j] * p[j];
            }
            #pragma unroll
            for (int off = 32; off; off >>= 1) ss += __shfl_xor(ss, off);
            float inv = 1.0f / fmaxf(sqrtf(ss), 1e-12f);
            #pragma unroll
            for (int j = 0; j < 8; ++j) p[j] *= inv;
        }
    }
    #pragma unroll
    for (int j = 0; j < 8; ++j)
        Phi8[(size_t)row * FEAT + j * 64 + lane] = f2fp8(p[j]);
}

// ---------------- Kernel 2: 256x128 rect Gram tiles, fp8-pair, ring-3 ------
// K=64 slots; LDS byte-geometry identical to R7's verified 0-conflict layout
// (64 B rows, 16 B XOR segments, ds_read_b128). Each b128 = global elements
// [16h,16h+16): low 8 B -> MFMA#0, high 8 B -> MFMA#1 (same (h,j)->k map for
// A and B => Gram correct; both halves cover all 64 k exactly once).
// Ring of 3 slots, staged 2 ahead, uniform 3 loads/wave/slot, vmcnt(3).
__global__ __launch_bounds__(512, 4) void gemm_disp_kernel(
    const unsigned char* __restrict__ Phi8, float* __restrict__ rowsum) {
    __shared__ __align__(16) char smem[3 * SLOTB];   // 72 KiB

    // XCD-aware swizzle (1056 = 8*132)
    int bid = blockIdx.x;
    int u = (bid & 7) * (NBLK / 8) + (bid >> 3);
    int i = 0;
    while (u >= NTJ - 2 * i) { u -= NTJ - 2 * i; ++i; }
    const int j = 2 * i + u;                // j >= 2i
    const bool diagovl = ((j >> 1) == i);   // col-range overlaps row-range

    const int w    = threadIdx.x >> 6;      // wave 0..7
    const int lane = threadIdx.x & 63;
    const int wr = w >> 1, wc = w & 1;      // 4x2 waves, 64x64 each
    const int h = lane >> 4;                // k-group 0..3
    const int r = lane & 15;                // fragment row/col
    const int rseg = (h ^ ((r >> 1) & 3)) * 16;  // swizzled 16B segment

    const int Ibase = i * 256, Jbase = j * 128;

    f32x4 acc[4][4];
    #pragma unroll
    for (int m = 0; m < 4; ++m)
        #pragma unroll
        for (int n = 0; n < 4; ++n) acc[m][n] = (f32x4){0.f, 0.f, 0.f, 0.f};

    // staging: per slot 24 KB = 24 wave-loads -> uniform 3/wave:
    // A (16 KB): 2 loads, rows w*32+c*16+(lane>>2); B (8 KB): 1 load,
    // rows w*16+(lane>>2). 4 lanes/row, 16B blocks, source pre-swizzled.
    const int srow = lane >> 2;             // 0..15
    const int sseg = (lane & 3) ^ ((lane >> 3) & 3);
    const unsigned char* gA =
        Phi8 + (size_t)(Ibase + w * 32 + srow) * FEAT + sseg * 16;
    const unsigned char* gB =
        Phi8 + (size_t)(Jbase + w * 16 + srow) * FEAT + sseg * 16;

#define STAGE(s)                                                              \
    {                                                                         \
        char* base = smem + ((s) % 3) * SLOTB;                                \
        __builtin_amdgcn_global_load_lds(                                     \
            (const __attribute__((address_space(1))) void*)(gA + (s) * 64),   \
            (__attribute__((address_space(3))) void*)(base + w * 2048),       \
            16, 0, 0);                                                        \
        __builtin_amdgcn_global_load_lds(                                     \
            (const __attribute__((address_space(1))) void*)(gA + 16 * FEAT + (s) * 64), \
            (__attribute__((address_space(3))) void*)(base + w * 2048 + 1024),\
            16, 0, 0);                                                        \
        __builtin_amdgcn_global_load_lds(                                     \
            (const __attribute__((address_space(1))) void*)(gB + (s) * 64),   \
            (__attribute__((address_space(3))) void*)(base + 16384 + w * 1024),\
            16, 0, 0);                                                        \
    }

#define MF8(ai, bi, mi, ni)                                                   \
    acc[mi][ni] = __builtin_amdgcn_mfma_f32_16x16x32_fp8_fp8(                 \
        ai[0], bi[0], acc[mi][ni], 0, 0, 0);                                  \
    acc[mi][ni] = __builtin_amdgcn_mfma_f32_16x16x32_fp8_fp8(                 \
        ai[1], bi[1], acc[mi][ni], 0, 0, 0);

#define SLOT(s, TAIL)                                                         \
    {                                                                         \
        const char* As = smem + ((s) % 3) * SLOTB;                            \
        const char* Bs = As + 16384;                                          \
        longx2 a0, a1, a2, a3, b0, b1, b2, b3;                                \
        b0 = *(const longx2*)(Bs + (wc * 64 +  0 + r) * 64 + rseg);           \
        b1 = *(const longx2*)(Bs + (wc * 64 + 16 + r) * 64 + rseg);           \
        b2 = *(const longx2*)(Bs + (wc * 64 + 32 + r) * 64 + rseg);           \
        b3 = *(const longx2*)(Bs + (wc * 64 + 48 + r) * 64 + rseg);           \
        a0 = *(const longx2*)(As + (wr * 64 +  0 + r) * 64 + rseg);           \
        a1 = *(const longx2*)(As + (wr * 64 + 16 + r) * 64 + rseg);           \
        a2 = *(const longx2*)(As + (wr * 64 + 32 + r) * 64 + rseg);           \
        a3 = *(const longx2*)(As + (wr * 64 + 48 + r) * 64 + rseg);           \
        __builtin_amdgcn_s_setprio(1);                                        \
        MF8(a0, b0, 0, 0) MF8(a1, b0, 1, 0) MF8(a2, b0, 2, 0) MF8(a3, b0, 3, 0) \
        MF8(a0, b1, 0, 1) MF8(a1, b1, 1, 1) MF8(a2, b1, 2, 1) MF8(a3, b1, 3, 1) \
        MF8(a0, b2, 0, 2) MF8(a1, b2, 1, 2) MF8(a2, b2, 2, 2) MF8(a3, b2, 3, 2) \
        MF8(a0, b3, 0, 3) MF8(a1, b3, 1, 3) MF8(a2, b3, 2, 3) MF8(a3, b3, 3, 3) \
        __builtin_amdgcn_s_setprio(0);                                        \
        TAIL                                                                  \
    }

#define TAIL_MID(s)                                                           \
    STAGE((s) + 2)                                                            \
    asm volatile("s_waitcnt vmcnt(3)" ::: "memory");                          \
    __builtin_amdgcn_s_barrier();
#define TAIL_6                                                                \
    asm volatile("s_waitcnt vmcnt(0)" ::: "memory");                          \
    __builtin_amdgcn_s_barrier();
#define TAIL_7

    // prologue: stage slots 0,1; wait slot 0 landed (slot 1 stays in flight)
    STAGE(0) STAGE(1)
    asm volatile("s_waitcnt vmcnt(3)" ::: "memory");
    __builtin_amdgcn_s_barrier();

    SLOT(0, TAIL_MID(0)) SLOT(1, TAIL_MID(1)) SLOT(2, TAIL_MID(2))
    SLOT(3, TAIL_MID(3)) SLOT(4, TAIL_MID(4)) SLOT(5, TAIL_MID(5))
    SLOT(6, TAIL_6)
    SLOT(7, TAIL_7)

    // epilogue: e = exp(10*S); zero exact diagonal on overlap blocks
    // D layout: row = 4*h + q, col = r (HW-verified, dtype-independent)
    #pragma unroll
    for (int m = 0; m < 4; ++m)
        #pragma unroll
        for (int n = 0; n < 4; ++n)
            #pragma unroll
            for (int q = 0; q < 4; ++q) {
                float v = __expf(acc[m][n][q] * 10.0f);
                if (diagovl &&
                    (Ibase + wr * 64 + m * 16 + h * 4 + q) ==
                    (Jbase + wc * 64 + n * 16 + r))
                    v = 0.f;
                acc[m][n][q] = v;
            }

    // row credit (always): rowsum[Ibase + wr*64 + m*16 + 4h+q]
    #pragma unroll
    for (int m = 0; m < 4; ++m) {
        float rs[4];
        #pragma unroll
        for (int q = 0; q < 4; ++q)
            rs[q] = acc[m][0][q] + acc[m][1][q] + acc[m][2][q] + acc[m][3][q];
        #pragma unroll
        for (int q = 0; q < 4; ++q)
            #pragma unroll
            for (int off = 1; off < 16; off <<= 1) rs[q] += __shfl_xor(rs[q], off);
        if (r == 0) {
            #pragma unroll
            for (int q = 0; q < 4; ++q)
                atomicAdd(&rowsum[Ibase + wr * 64 + m * 16 + h * 4 + q], rs[q]);
        }
    }

    // col credit (only when mirror entry is NOT computed elsewhere): j >= 2i+2
    if (!diagovl) {
        #pragma unroll
        for (int n = 0; n < 4; ++n) {
            float cs = 0.f;
            #pragma unroll
            for (int m = 0; m < 4; ++m)
                #pragma unroll
                for (int q = 0; q < 4; ++q) cs += acc[m][n][q];
            cs += __shfl_xor(cs, 16);
            cs += __shfl_xor(cs, 32);
            if (lane < 16)
                atomicAdd(&rowsum[Jbase + wc * 64 + n * 16 + r], cs);
        }
    }
}

// ---------------- Kernel 3: loss = mean(log(rowsum / (n-1))) ---------------
__global__ __launch_bounds__(512) void loss_kernel(
    const float* __restrict__ rowsum, float* __restrict__ out) {
    __shared__ float red[8];
    float s = 0.f;
    for (int i = threadIdx.x; i < N_CLS; i += 512)
        s += logf(rowsum[i] * (1.0f / (float)(N_CLS - 1)));
    #pragma unroll
    for (int off = 32; off; off >>= 1) s += __shfl_xor(s, off);
    if ((threadIdx.x & 63) == 0) red[threadIdx.x >> 6] = s;
    __syncthreads();
    if (threadIdx.x == 0) {
        float tot = 0.f;
        #pragma unroll
        for (int i = 0; i < 8; ++i) tot += red[i];
        out[0] = tot * (1.0f / (float)N_CLS);
    }
}

extern "C" void kernel_launch(void* const* d_in, const int* in_sizes, int n_in,
                              void* d_out, int out_size, void* d_ws, size_t ws_size,
                              hipStream_t stream) {
    (void)in_sizes; (void)n_in; (void)out_size; (void)ws_size;
    const float* features = (const float*)d_in[0];
    const int*   labels   = (const int*)d_in[1];
    const float* protos   = (const float*)d_in[2];
    float* out = (float*)d_out;

    unsigned char* Phi8 = (unsigned char*)d_ws;                     // 4 MiB
    float* rowsum = (float*)(Phi8 + (size_t)N_CLS * FEAT);          // 32 KiB

    ema_kernel<<<N_CLS / 4, 256, 0, stream>>>(features, labels, protos, Phi8, rowsum);
    gemm_disp_kernel<<<NBLK, 512, 0, stream>>>(Phi8, rowsum);
    loss_kernel<<<1, 512, 0, stream>>>(rowsum, out);
}